// Round 4
// baseline (213.503 us; speedup 1.0000x reference)
//
#include <hip/hip_runtime.h>

#define TINYF 1e-8f
#define NITER 50

typedef __attribute__((ext_vector_type(2))) float v2f;

__device__ __forceinline__ float dpp_shr1_s(float v) {
    return __int_as_float(__builtin_amdgcn_update_dpp(0, __float_as_int(v), 0x111, 0xf, 0xf, true));
}
__device__ __forceinline__ float dpp_shl1_s(float v) {
    return __int_as_float(__builtin_amdgcn_update_dpp(0, __float_as_int(v), 0x101, 0xf, 0xf, true));
}
// lane i <- lane i-1 / i+1 within 16-lane DPP row; 0 at row edge (= crop L/R edge)
__device__ __forceinline__ v2f dpp_shr1(v2f v) {
    v2f r; r.x = dpp_shr1_s(v.x); r.y = dpp_shr1_s(v.y); return r;
}
__device__ __forceinline__ v2f dpp_shl1(v2f v) {
    v2f r; r.x = dpp_shl1_s(v.x); r.y = dpp_shl1_s(v.y); return r;
}
__device__ __forceinline__ v2f bperm2(int addr4, v2f v) {
    v2f r;
    r.x = __int_as_float(__builtin_amdgcn_ds_bpermute(addr4, __float_as_int(v.x)));
    r.y = __int_as_float(__builtin_amdgcn_ds_bpermute(addr4, __float_as_int(v.y)));
    return r;
}
__device__ __forceinline__ v2f rcp2(v2f v) {
    v2f r; r.x = __builtin_amdgcn_rcpf(v.x); r.y = __builtin_amdgcn_rcpf(v.y); return r;
}

// full prep: s1 (|dx|=1 pairs) + s2 (|dx|=2 pairs) for this lane's 3 cols
#define PREPF(C0_, C1_, C2_) \
    L2 = dpp_shr1(C1_); L1 = dpp_shr1(C2_); R1 = dpp_shl1(C0_); R2 = dpp_shl1(C1_); \
    s1a = L1 + C1_; s1b = C0_ + C2_; s1c = C1_ + R1; \
    s2a = L2 + C2_; s2b = L1 + R1; s2c = C0_ + R2;
#define PREPS(C0_, C1_, C2_) \
    L1 = dpp_shr1(C2_); R1 = dpp_shl1(C0_); \
    s1a = L1 + C1_; s1b = C0_ + C2_; s1c = C1_ + R1;
#define AT0(I, C0_, C1_, C2_, KA, KB, KC) \
    acc[I][0] += KA * C0_ + KB * s1a + KC * s2a; \
    acc[I][1] += KA * C1_ + KB * s1b + KC * s2b; \
    acc[I][2] += KA * C2_ + KB * s1c + KC * s2c;
#define AT0I(I, C0_, C1_, C2_, KA, KB, KC) \
    acc[I][0] = KA * C0_ + KB * s1a + KC * s2a; \
    acc[I][1] = KA * C1_ + KB * s1b + KC * s2b; \
    acc[I][2] = KA * C2_ + KB * s1c + KC * s2c;
#define AT1(I, C0_, C1_, C2_, KA, KB) \
    acc[I][0] += KA * C0_ + KB * s1a; \
    acc[I][1] += KA * C1_ + KB * s1b; \
    acc[I][2] += KA * C2_ + KB * s1c;
#define AT1I(I, C0_, C1_, C2_, KA, KB) \
    acc[I][0] = KA * C0_ + KB * s1a; \
    acc[I][1] = KA * C1_ + KB * s1b; \
    acc[I][2] = KA * C2_ + KB * s1c;
#define AT2(I, C0_, C1_, C2_, KA) \
    acc[I][0] += KA * C0_; \
    acc[I][1] += KA * C1_; \
    acc[I][2] += KA * C2_;
#define AT2I(I, C0_, C1_, C2_, KA) \
    acc[I][0] = KA * C0_; \
    acc[I][1] = KA * C1_; \
    acc[I][2] = KA * C2_;

// 4 waves = TWO 48x48 crops, packed: lane component .x = crop 2g, .y = crop
// 2g+1. Wave W owns rows [12W,12W+12) of both. Exact round-2 (verified)
// exchange: band halos via ds_bpermute, wave halos via parity-double-buffered
// LDS, 1 barrier per half-iteration. The two packed streams are independent ->
// every FMA/ADD is a v_pk_*_f32 on independent data, filling the dependency
// stalls that kept per-wave busy at ~43-25% in rounds 0-2.
__global__ void __launch_bounds__(256, 2)
sinkhorn_pk(const float* __restrict__ hm_gt,
            const float* __restrict__ hm_pred,
            const int* __restrict__ tops,
            float* __restrict__ out) {
    // EXP[parity][W][slot][96]: per slot-row, cols0,1 packed {A,B} as float4 at
    // [c*4], col2 packed {A,B} as float2 at [64+c*2].
    // slots 0,1 = wave rows 0,1; slots 2,3 = wave rows 10,11.
    __shared__ __align__(16) float EXP[2][4][4][96];
    __shared__ v2f sredA[4], sredB[4];
    __shared__ float slw[4];

    const int t = threadIdx.x;
    const int W = t >> 6;                  // wave 0..3
    const int l = t & 63;
    const int b = l >> 4, c = l & 15;      // band (3 rows) x colgroup (3 cols)
    const bool btop = (b == 0), bbot = (b == 3);
    const bool wtop = (W == 0), wbot = (W == 3);
    const int upA = ((l - 16) & 63) << 2;
    const int dnA = ((l + 16) & 63) << 2;

    const int g = blockIdx.x;              // crops 2g (.x) and 2g+1 (.y)
    const int k0 = 2 * g, k1 = 2 * g + 1;
    const int bi0 = k0 / 40, rr0 = (k0 / 5) % 8, cc0 = k0 % 5;
    const int bi1 = k1 / 40, rr1 = (k1 / 5) % 8, cc1 = k1 % 5;
    const int y00 = tops[(bi0 * 8 + rr0) * 2 + 0];
    const int x00 = tops[(bi0 * 8 + rr0) * 2 + 1];
    const int y01 = tops[(bi1 * 8 + rr1) * 2 + 0];
    const int x01 = tops[(bi1 * 8 + rr1) * 2 + 1];
    const float* gt0 = hm_gt   + (size_t)(bi0 * 5 + cc0) * 25600;
    const float* pr0 = hm_pred + (size_t)(bi0 * 5 + cc0) * 25600;
    const float* gt1 = hm_gt   + (size_t)(bi1 * 5 + cc1) * 25600;
    const float* pr1 = hm_pred + (size_t)(bi1 * 5 + cc1) * 25600;

    // ---- load own 3x3 tiles of both crops (both maps); block-reduce sums ----
    v2f va[3][3], vb[3][3];
    v2f sA = {0.f, 0.f}, sB = {0.f, 0.f};
    const int rb0 = y00 + 12 * W + 3 * b;
    const int rb1 = y01 + 12 * W + 3 * b;
#pragma unroll
    for (int i = 0; i < 3; ++i) {
        const int g0 = (rb0 + i) * 160 + x00 + 3 * c;
        const int g1 = (rb1 + i) * 160 + x01 + 3 * c;
#pragma unroll
        for (int j = 0; j < 3; ++j) {
            v2f A, B;
            A.x = gt0[g0 + j]; A.y = gt1[g1 + j];
            B.x = pr0[g0 + j]; B.y = pr1[g1 + j];
            va[i][j] = A; vb[i][j] = B;
            sA += A; sB += B;
        }
    }
#pragma unroll
    for (int o = 1; o < 64; o <<= 1) {
        sA.x += __shfl_xor(sA.x, o, 64); sA.y += __shfl_xor(sA.y, o, 64);
        sB.x += __shfl_xor(sB.x, o, 64); sB.y += __shfl_xor(sB.y, o, 64);
    }
    if (l == 0) { sredA[W] = sA; sredB[W] = sB; }
    __syncthreads();
    sA = sredA[0] + sredA[1] + sredA[2] + sredA[3];
    sB = sredB[0] + sredB[1] + sredB[2] + sredB[3];
    v2f nA, nB;
    nA.x = 1.0f / (sA.x + TINYF); nA.y = 1.0f / (sA.y + TINYF);
    nB.x = 1.0f / (sB.x + TINYF); nB.y = 1.0f / (sB.y + TINYF);
#pragma unroll
    for (int i = 0; i < 3; ++i)
#pragma unroll
        for (int j = 0; j < 3; ++j) { va[i][j] *= nA; vb[i][j] *= nB; }

    // Gibbs weights (same expressions as before -> same rounding)
    const float e10 = expf(-1.0f / 0.1f);
    const float e2  = expf(-sqrtf(2.0f) / 0.1f);
    const float e20 = expf(-2.0f / 0.1f);

    v2f xu[3][3], xv[3][3], acc[3][3];
    const float u0 = 1.0f / 2304.0f;
#pragma unroll
    for (int i = 0; i < 3; ++i)
#pragma unroll
        for (int j = 0; j < 3; ++j) { xu[i][j].x = u0; xu[i][j].y = u0; }

    // publish boundary rows of field y into parity buffer p, then sync
    auto publish = [&](const v2f (&y)[3][3], int p) {
        if (btop) {
            *(float4*)&EXP[p][W][0][c * 4] = make_float4(y[0][0].x, y[0][0].y, y[0][1].x, y[0][1].y);
            *(v2f*)&EXP[p][W][0][64 + c * 2] = y[0][2];
            *(float4*)&EXP[p][W][1][c * 4] = make_float4(y[1][0].x, y[1][0].y, y[1][1].x, y[1][1].y);
            *(v2f*)&EXP[p][W][1][64 + c * 2] = y[1][2];
        }
        if (bbot) {
            *(float4*)&EXP[p][W][2][c * 4] = make_float4(y[1][0].x, y[1][0].y, y[1][1].x, y[1][1].y);
            *(v2f*)&EXP[p][W][2][64 + c * 2] = y[1][2];
            *(float4*)&EXP[p][W][3][c * 4] = make_float4(y[2][0].x, y[2][0].y, y[2][1].x, y[2][1].y);
            *(v2f*)&EXP[p][W][3][64 + c * 2] = y[2][2];
        }
        __syncthreads();
    };

    auto readrow = [&](int p, int w, int slot, v2f (&q)[3]) {
        const float4 f = *(const float4*)&EXP[p][w][slot][c * 4];
        q[0].x = f.x; q[0].y = f.y; q[1].x = f.z; q[1].y = f.w;
        q[2] = *(const v2f*)&EXP[p][w][slot][64 + c * 2];
    };

    // exact 13-tap conv (verified round-2 structure, packed)
    auto conv = [&](const v2f (&x)[3][3], int p,
                    float K00, float K01, float K02,
                    float K10, float K11, float K20) {
        v2f qA[3] = {}, qB[3] = {}, qC[3] = {}, qD[3] = {};
        if (btop && !wtop) { readrow(p, W - 1, 2, qA); readrow(p, W - 1, 3, qB); }
        if (bbot && !wbot) { readrow(p, W + 1, 0, qC); readrow(p, W + 1, 1, qD); }
        v2f tA[3], tB[3], tC[3], tD[3];
#pragma unroll
        for (int j = 0; j < 3; ++j) {
            tA[j] = bperm2(upA, x[1][j]);  // local row -2
            tB[j] = bperm2(upA, x[2][j]);  // local row -1
            tC[j] = bperm2(dnA, x[0][j]);  // local row 3
            tD[j] = bperm2(dnA, x[1][j]);  // local row 4
        }

        v2f L1, L2, R1, R2, s1a, s1b, s1c, s2a, s2b, s2c;
        // own rows first (no DS dependence -> hides bperm/LDS latency)
        PREPF(x[0][0], x[0][1], x[0][2])                        // w=0
        AT0I(0, x[0][0], x[0][1], x[0][2], K00, K01, K02)
        AT1I(1, x[0][0], x[0][1], x[0][2], K10, K11)
        AT2I(2, x[0][0], x[0][1], x[0][2], K20)
        PREPF(x[1][0], x[1][1], x[1][2])                        // w=1
        AT1(0, x[1][0], x[1][1], x[1][2], K10, K11)
        AT0(1, x[1][0], x[1][1], x[1][2], K00, K01, K02)
        AT1(2, x[1][0], x[1][1], x[1][2], K10, K11)
        PREPF(x[2][0], x[2][1], x[2][2])                        // w=2
        AT2(0, x[2][0], x[2][1], x[2][2], K20)
        AT1(1, x[2][0], x[2][1], x[2][2], K10, K11)
        AT0(2, x[2][0], x[2][1], x[2][2], K00, K01, K02)

        // resolve halos (band edge: intra-wave bperm or inter-wave LDS / zero)
        v2f hA[3], hB[3], hC[3], hD[3];
#pragma unroll
        for (int j = 0; j < 3; ++j) {
            hA[j] = btop ? qA[j] : tA[j];
            hB[j] = btop ? qB[j] : tB[j];
            hC[j] = bbot ? qC[j] : tC[j];
            hD[j] = bbot ? qD[j] : tD[j];
        }
        PREPS(hB[0], hB[1], hB[2])          // row -1
        AT1(0, hB[0], hB[1], hB[2], K10, K11)
        AT2(1, hB[0], hB[1], hB[2], K20)
        AT2(0, hA[0], hA[1], hA[2], K20)    // row -2
        PREPS(hC[0], hC[1], hC[2])          // row 3
        AT2(1, hC[0], hC[1], hC[2], K20)
        AT1(2, hC[0], hC[1], hC[2], K10, K11)
        AT2(2, hD[0], hD[1], hD[2], K20)    // row 4
    };

    // seed parity-0 buffer with u0 boundary rows
    publish(xu, 0);

    // ---- Sinkhorn iterations: 1 barrier per half-iteration ----
#pragma unroll 1
    for (int it = 0; it < NITER; ++it) {
        conv(xu, 0, 1.0f, e10, e20, e10, e2, e20);
#pragma unroll
        for (int i = 0; i < 3; ++i)
#pragma unroll
            for (int j = 0; j < 3; ++j)
                xv[i][j] = vb[i][j] * rcp2(acc[i][j] + TINYF);
        publish(xv, 1);

        conv(xv, 1, 1.0f, e10, e20, e10, e2, e20);
#pragma unroll
        for (int i = 0; i < 3; ++i)
#pragma unroll
            for (int j = 0; j < 3; ++j)
                xu[i][j] = va[i][j] * rcp2(acc[i][j] + TINYF);
        publish(xu, 0);
    }

    // ---- loss: (u @ M) . v, M = K .* dist (center 0; e5/e8 taps dropped) ----
    const float s2f = sqrtf(2.0f);
    const float m01 = e10, m02 = e20 * 2.0f, m11 = e2 * s2f;
    conv(xu, 0, 0.0f, m01, m02, m01, m11, m02);
    v2f lsum2 = {0.f, 0.f};
#pragma unroll
    for (int i = 0; i < 3; ++i)
#pragma unroll
        for (int j = 0; j < 3; ++j)
            lsum2 += acc[i][j] * xv[i][j];
    float lsum = lsum2.x + lsum2.y;

#pragma unroll
    for (int o = 1; o < 64; o <<= 1) lsum += __shfl_xor(lsum, o, 64);
    if (l == 0) slw[W] = lsum;
    __syncthreads();
    if (t == 0)
        atomicAdd(out, slw[0] + slw[1] + slw[2] + slw[3]);
}

extern "C" void kernel_launch(void* const* d_in, const int* in_sizes, int n_in,
                              void* d_out, int out_size, void* d_ws, size_t ws_size,
                              hipStream_t stream) {
    (void)in_sizes; (void)n_in; (void)out_size; (void)d_ws; (void)ws_size;
    const float* hm_gt = (const float*)d_in[0];
    const float* hm_pred = (const float*)d_in[1];
    const int* tops = (const int*)d_in[2];
    float* out = (float*)d_out;

    hipMemsetAsync(out, 0, sizeof(float), stream);
    sinkhorn_pk<<<dim3(320), dim3(256), 0, stream>>>(hm_gt, hm_pred, tops, out);
}

// Round 5
// 198.224 us; speedup vs baseline: 1.0771x; 1.0771x over previous
//
#include <hip/hip_runtime.h>

#define TINYF 1e-8f
#define NITER 50

// Wave-wide DPP shifts (gfx9 lineage dpp_ctrl: 0x138 = wave_shr1, 0x130 = wave_shl1).
// wW: lane i <- lane i-1 (west neighbor value), 0 shifted into lane 0.
// wE: lane i <- lane i+1 (east neighbor value), 0 shifted into lane 63.
// (Fallback if these ctrls are rejected on gfx950: ds_bpermute with addr (l+/-1)&63.)
__device__ __forceinline__ float wW(float v) {
    return __int_as_float(__builtin_amdgcn_update_dpp(0, __float_as_int(v), 0x138, 0xf, 0xf, true));
}
__device__ __forceinline__ float wE(float v) {
    return __int_as_float(__builtin_amdgcn_update_dpp(0, __float_as_int(v), 0x130, 0xf, 0xf, true));
}

// Column-per-lane layout: 8 waves = one 48x48 crop. Wave W owns rows
// [6W, 6W+6), lane l (0..47) owns column l; lanes 48-63 idle (kept zero).
// Vertical taps: pure register references. Horizontal taps: wave-wide DPP
// shifts (VALU pipe -> zero DS-pipe traffic, no bperm). Inter-wave halos
// (rows -2,-1,+6,+7): LDS with zero-guard slots, parity-double-buffered,
// ONE barrier per half-iteration. 5120 waves = ~5 waves/SIMD of TLP.
__global__ void __launch_bounds__(512)
__attribute__((amdgpu_waves_per_eu(6)))
sinkhorn_col(const float* __restrict__ hm_gt,
             const float* __restrict__ hm_pred,
             const int* __restrict__ tops,
             float* __restrict__ out) {
    // EX[parity][slot 0..9][4 rows][64 cols]; slot = W+1; slots 0,9 = zero guards.
    // rows 0,1 = wave rows 0,1 (read as +6,+7 by wave below);
    // rows 2,3 = wave rows 4,5 (read as -2,-1 by wave above).
    __shared__ float EX[2][10][4][64];
    __shared__ float sred[2][8];

    const int t = threadIdx.x;
    const int W = t >> 6;                  // wave 0..7: rows [6W, 6W+6)
    const int l = t & 63;                  // column (0..47 active)
    const bool act = (l < 48);

    // zero the guard slots (both parities): slot0 rows 2,3 ; slot9 rows 0,1
    {
        const int p = t >> 8, q = (t >> 6) & 3, ln = t & 63;
        if (q < 2) EX[p][0][2 + q][ln] = 0.f;
        else       EX[p][9][q - 2][ln] = 0.f;
    }

    const int blk = blockIdx.x;            // ((bi*8+rr)*5+cc)
    const int bi = blk / 40, rr = (blk / 5) % 8, cc = blk % 5;
    const int y0 = tops[(bi * 8 + rr) * 2 + 0];
    const int x0 = tops[(bi * 8 + rr) * 2 + 1];
    const float* srcA = hm_gt + (size_t)(bi * 5 + cc) * 25600;
    const float* srcB = hm_pred + (size_t)(bi * 5 + cc) * 25600;

    // ---- load own column segment of both crops; block-reduce sums ----
    float va[6], vb[6];
    float sA = 0.f, sB = 0.f;
    const int rbase = y0 + 6 * W;
#pragma unroll
    for (int r = 0; r < 6; ++r) {
        const int g = (rbase + r) * 160 + x0 + l;   // in-bounds even for idle lanes
        const float A = act ? srcA[g] : 0.f;
        const float B = act ? srcB[g] : 0.f;
        va[r] = A; vb[r] = B;
        sA += A; sB += B;
    }
#pragma unroll
    for (int o = 1; o < 64; o <<= 1) {
        sA += __shfl_xor(sA, o, 64);
        sB += __shfl_xor(sB, o, 64);
    }
    if (l == 0) { sred[0][W] = sA; sred[1][W] = sB; }
    __syncthreads();                       // also makes guard zeros visible
    sA = 0.f; sB = 0.f;
#pragma unroll
    for (int w = 0; w < 8; ++w) { sA += sred[0][w]; sB += sred[1][w]; }
    const float nA = 1.0f / (sA + TINYF);
    const float nB = 1.0f / (sB + TINYF);
#pragma unroll
    for (int r = 0; r < 6; ++r) { va[r] *= nA; vb[r] *= nB; }

    // Gibbs weights (same expressions as the verified rounds -> same values)
    const float e10 = expf(-1.0f / 0.1f);
    const float e2  = expf(-sqrtf(2.0f) / 0.1f);
    const float e20 = expf(-2.0f / 0.1f);

    float xu[6], xv[6], acc[6];
    const float u0 = 1.0f / 2304.0f;
#pragma unroll
    for (int r = 0; r < 6; ++r) xu[r] = act ? u0 : 0.f;

    // publish boundary rows of field y into parity buffer p, then sync
    auto publish = [&](const float (&y)[6], int p) {
        EX[p][W + 1][0][l] = y[0];
        EX[p][W + 1][1][l] = y[1];
        EX[p][W + 1][2][l] = y[4];
        EX[p][W + 1][3][l] = y[5];
        __syncthreads();
    };

    // 13-tap conv: center(K00=CENTER?1:0) + K01*(N,S,E,W) + K11*(4 diag)
    //            + K02*(NN,SS,EE,WW). Corners e5/e8 dropped (as verified).
    auto conv = [&](const float (&x)[6], int p, bool CENTER,
                    float K01, float K11, float K02) {
        // inter-wave halo rows (guards give 0 at crop top/bottom)
        const float hm2 = EX[p][W][2][l];       // crop row 6W-2
        const float hm1 = EX[p][W][3][l];       // crop row 6W-1
        const float hp6 = EX[p][W + 2][0][l];   // crop row 6W+6
        const float hp7 = EX[p][W + 2][1][l];   // crop row 6W+7
        // horizontal shifted sums (wave-wide DPP; crop L/R edges -> 0)
        float s1[8], s2[6];                     // s1[k] = row (k-1) |dx|=1 sum
#pragma unroll
        for (int r = 0; r < 6; ++r) {
            const float w1 = wW(x[r]), e1 = wE(x[r]);
            s1[r + 1] = w1 + e1;
            s2[r] = wW(w1) + wE(e1);
        }
        s1[0] = wW(hm1) + wE(hm1);
        s1[7] = wW(hp6) + wE(hp6);
        // combine (all vertical taps are register/halo references)
#pragma unroll
        for (int r = 0; r < 6; ++r) {
            const float up1 = (r == 0) ? hm1 : x[r - 1];
            const float dn1 = (r == 5) ? hp6 : x[r + 1];
            const float up2 = (r == 0) ? hm2 : ((r == 1) ? hm1 : x[r - 2]);
            const float dn2 = (r == 4) ? hp6 : ((r == 5) ? hp7 : x[r + 2]);
            float a = CENTER ? x[r] : 0.f;
            a = fmaf(K01, s1[r + 1] + (up1 + dn1), a);
            a = fmaf(K11, s1[r] + s1[r + 2], a);
            a = fmaf(K02, s2[r] + (up2 + dn2), a);
            acc[r] = a;
        }
    };

    // seed parity-0 buffer with u0 boundary rows
    publish(xu, 0);

    // ---- Sinkhorn iterations: 1 barrier per half-iteration ----
#pragma unroll 1
    for (int it = 0; it < NITER; ++it) {
        conv(xu, 0, true, e10, e2, e20);
#pragma unroll
        for (int r = 0; r < 6; ++r)
            xv[r] = vb[r] * __builtin_amdgcn_rcpf(acc[r] + TINYF);
        publish(xv, 1);

        conv(xv, 1, true, e10, e2, e20);
#pragma unroll
        for (int r = 0; r < 6; ++r)
            xu[r] = va[r] * __builtin_amdgcn_rcpf(acc[r] + TINYF);
        publish(xu, 0);
    }

    // ---- loss: (u @ M) . v, M = K .* dist (center 0; e5/e8 taps dropped) ----
    const float s2f = sqrtf(2.0f);
    const float m01 = e10, m02 = e20 * 2.0f, m11 = e2 * s2f;
    conv(xu, 0, false, m01, m11, m02);
    float lsum = 0.f;
#pragma unroll
    for (int r = 0; r < 6; ++r) lsum += acc[r] * xv[r];

#pragma unroll
    for (int o = 1; o < 64; o <<= 1) lsum += __shfl_xor(lsum, o, 64);
    if (l == 0) sred[0][W] = lsum;
    __syncthreads();
    if (t == 0) {
        float s = 0.f;
#pragma unroll
        for (int w = 0; w < 8; ++w) s += sred[0][w];
        atomicAdd(out, s);
    }
}

extern "C" void kernel_launch(void* const* d_in, const int* in_sizes, int n_in,
                              void* d_out, int out_size, void* d_ws, size_t ws_size,
                              hipStream_t stream) {
    (void)in_sizes; (void)n_in; (void)out_size; (void)d_ws; (void)ws_size;
    const float* hm_gt = (const float*)d_in[0];
    const float* hm_pred = (const float*)d_in[1];
    const int* tops = (const int*)d_in[2];
    float* out = (float*)d_out;

    hipMemsetAsync(out, 0, sizeof(float), stream);
    sinkhorn_col<<<dim3(640), dim3(512), 0, stream>>>(hm_gt, hm_pred, tops, out);
}

// Round 6
// 172.348 us; speedup vs baseline: 1.2388x; 1.1501x over previous
//
#include <hip/hip_runtime.h>

#define TINYF 1e-8f
#define NITER 50

typedef __attribute__((ext_vector_type(2))) float v2f;

// Wave-wide DPP shifts (verified on gfx950 in round 5): 0x138 = wave_shr1
// (lane i <- i-1, 0 into lane 0), 0x130 = wave_shl1 (lane i <- i+1, 0 into 63).
__device__ __forceinline__ float wWs(float v) {
    return __int_as_float(__builtin_amdgcn_update_dpp(0, __float_as_int(v), 0x138, 0xf, 0xf, true));
}
__device__ __forceinline__ float wEs(float v) {
    return __int_as_float(__builtin_amdgcn_update_dpp(0, __float_as_int(v), 0x130, 0xf, 0xf, true));
}
__device__ __forceinline__ v2f wW(v2f v) { v2f r; r.x = wWs(v.x); r.y = wWs(v.y); return r; }
__device__ __forceinline__ v2f wE(v2f v) { v2f r; r.x = wEs(v.x); r.y = wEs(v.y); return r; }
__device__ __forceinline__ v2f rcp2(v2f v) {
    v2f r; r.x = __builtin_amdgcn_rcpf(v.x); r.y = __builtin_amdgcn_rcpf(v.y); return r;
}
// packed fma: a*k + c  (k splatted) -> v_pk_fma_f32
__device__ __forceinline__ v2f pfma(float k, v2f a, v2f c) {
    v2f kv; kv.x = k; kv.y = k;
    return __builtin_elementwise_fma(kv, a, c);
}

// Column-per-lane + vertical 2-band packing: 4 waves = one 48x48 crop.
// Lane l (0..47) owns column l (lanes 48-63 idle/zero). Wave W holds rows
// [6W,6W+6) in .x and [24+6W,24+6W+6) in .y of each v2f register -> every
// add/fma is one v_pk_*_f32 for two rows. Horizontal taps: wave-wide DPP
// (VALU). Vertical taps: register refs. Inter-band halos: LDS slots
// ES[p][s].x = band s-1, ES[p][s].y = band s+3 -> one b64 write/read per
// boundary row; band3/band4 seam needs 2 extra scalar writes (waves 3,0).
// Grid 640 x 4 waves: same block/CU balance as round 5 with 0.66x the issue.
__global__ void __launch_bounds__(256)
sinkhorn_colpk(const float* __restrict__ hm_gt,
               const float* __restrict__ hm_pred,
               const int* __restrict__ tops,
               float* __restrict__ out) {
    __shared__ v2f ES[2][6][4][64];
    __shared__ float sred[2][4];

    const int t = threadIdx.x;
    const int W = t >> 6;                  // wave 0..3
    const int l = t & 63;                  // column (0..47 active)
    const bool act = (l < 48);

    // zero guards: .x of slot0 rows 2,3 (band -1) ; .y of slot5 rows 0,1 (band 8)
    {
        const int p = W >> 1, r = W & 1;
        ((float*)&ES[p][0][2 + r][l])[0] = 0.f;
        ((float*)&ES[p][5][r][l])[1] = 0.f;
    }

    const int blk = blockIdx.x;            // ((bi*8+rr)*5+cc)
    const int bi = blk / 40, rr = (blk / 5) % 8, cc = blk % 5;
    const int y0 = tops[(bi * 8 + rr) * 2 + 0];
    const int x0 = tops[(bi * 8 + rr) * 2 + 1];
    const float* srcA = hm_gt + (size_t)(bi * 5 + cc) * 25600;
    const float* srcB = hm_pred + (size_t)(bi * 5 + cc) * 25600;

    // ---- load own two 6-row column segments of both crops; block-reduce sums ----
    v2f va[6], vb[6];
    float sA = 0.f, sB = 0.f;
    const int rbx = y0 + 6 * W;            // .x band
    const int rby = y0 + 24 + 6 * W;       // .y band
#pragma unroll
    for (int r = 0; r < 6; ++r) {
        const int gx = (rbx + r) * 160 + x0 + l;
        const int gy = (rby + r) * 160 + x0 + l;
        va[r].x = act ? srcA[gx] : 0.f;
        va[r].y = act ? srcA[gy] : 0.f;
        vb[r].x = act ? srcB[gx] : 0.f;
        vb[r].y = act ? srcB[gy] : 0.f;
        sA += va[r].x + va[r].y;
        sB += vb[r].x + vb[r].y;
    }
#pragma unroll
    for (int o = 1; o < 64; o <<= 1) {
        sA += __shfl_xor(sA, o, 64);
        sB += __shfl_xor(sB, o, 64);
    }
    if (l == 0) { sred[0][W] = sA; sred[1][W] = sB; }
    __syncthreads();                       // also makes guard zeros visible
    sA = sred[0][0] + sred[0][1] + sred[0][2] + sred[0][3];
    sB = sred[1][0] + sred[1][1] + sred[1][2] + sred[1][3];
    const float nA = 1.0f / (sA + TINYF);
    const float nB = 1.0f / (sB + TINYF);
#pragma unroll
    for (int r = 0; r < 6; ++r) {
        va[r].x *= nA; va[r].y *= nA;
        vb[r].x *= nB; vb[r].y *= nB;
    }

    // Gibbs weights (same expressions as the verified rounds -> same values)
    const float e10 = expf(-1.0f / 0.1f);
    const float e2  = expf(-sqrtf(2.0f) / 0.1f);
    const float e20 = expf(-2.0f / 0.1f);

    v2f xu[6], xv[6], acc[6];
    const float u0 = 1.0f / 2304.0f;
#pragma unroll
    for (int r = 0; r < 6; ++r) { xu[r].x = act ? u0 : 0.f; xu[r].y = act ? u0 : 0.f; }

    // publish boundary rows of field y into parity buffer p, then sync.
    // Slot W+1 holds {band W (.x), band W+4 (.y)} = exactly this wave's y pair.
    auto publish = [&](const v2f (&y)[6], int p) {
        ES[p][W + 1][0][l] = y[0];
        ES[p][W + 1][1][l] = y[1];
        ES[p][W + 1][2][l] = y[4];
        ES[p][W + 1][3][l] = y[5];
        if (W == 3) {   // seam: band 3 rows 4,5 also needed at slot0 rows 2,3 (.y)
            ((float*)&ES[p][0][2][l])[1] = y[4].x;
            ((float*)&ES[p][0][3][l])[1] = y[5].x;
        }
        if (W == 0) {   // seam: band 4 rows 0,1 also needed at slot5 rows 0,1 (.x)
            ((float*)&ES[p][5][0][l])[0] = y[0].y;
            ((float*)&ES[p][5][1][l])[0] = y[1].y;
        }
        __syncthreads();
    };

    // 13-tap conv: CENTER*x + K01*(N,S,E,W) + K11*(diag) + K02*(NN,SS,EE,WW),
    // e5/e8 corners dropped (verified tap set). All combine math packed 2-wide.
    auto conv = [&](const v2f (&x)[6], int p, bool CENTER,
                    float K01, float K11, float K02) {
        // halo rows, both bands at once: .x = band W +/- , .y = band W+4 +/-
        const v2f um2 = ES[p][W][2][l];        // band rows -2
        const v2f um1 = ES[p][W][3][l];        // band rows -1
        const v2f up6 = ES[p][W + 2][0][l];    // band rows +6
        const v2f up7 = ES[p][W + 2][1][l];    // band rows +7
        // horizontal shifted sums (crop L/R edges -> 0 via bound_ctrl + idle lanes)
        v2f s1[8], s2[6];                      // s1[k] = row (k-1) |dx|=1 sum
#pragma unroll
        for (int r = 0; r < 6; ++r) {
            const v2f w1 = wW(x[r]), e1 = wE(x[r]);
            s1[r + 1] = w1 + e1;
            s2[r] = wW(w1) + wE(e1);
        }
        s1[0] = wW(um1) + wE(um1);
        s1[7] = wW(up6) + wE(up6);
#pragma unroll
        for (int r = 0; r < 6; ++r) {
            const v2f up1 = (r == 0) ? um1 : x[r - 1];
            const v2f dn1 = (r == 5) ? up6 : x[r + 1];
            const v2f up2 = (r == 0) ? um2 : ((r == 1) ? um1 : x[r - 2]);
            const v2f dn2 = (r == 4) ? up6 : ((r == 5) ? up7 : x[r + 2]);
            v2f a;
            if (CENTER) { a = x[r]; } else { a.x = 0.f; a.y = 0.f; }
            a = pfma(K01, s1[r + 1] + (up1 + dn1), a);
            a = pfma(K11, s1[r] + s1[r + 2], a);
            a = pfma(K02, s2[r] + (up2 + dn2), a);
            acc[r] = a;
        }
    };

    // seed parity-0 buffer with u0 boundary rows
    publish(xu, 0);

    // ---- Sinkhorn iterations: 1 barrier per half-iteration ----
#pragma unroll 1
    for (int it = 0; it < NITER; ++it) {
        conv(xu, 0, true, e10, e2, e20);
#pragma unroll
        for (int r = 0; r < 6; ++r) {
            v2f d; d.x = acc[r].x + TINYF; d.y = acc[r].y + TINYF;
            xv[r] = vb[r] * rcp2(d);
        }
        publish(xv, 1);

        conv(xv, 1, true, e10, e2, e20);
#pragma unroll
        for (int r = 0; r < 6; ++r) {
            v2f d; d.x = acc[r].x + TINYF; d.y = acc[r].y + TINYF;
            xu[r] = va[r] * rcp2(d);
        }
        publish(xu, 0);
    }

    // ---- loss: (u @ M) . v, M = K .* dist (center 0; e5/e8 taps dropped) ----
    const float s2f = sqrtf(2.0f);
    const float m01 = e10, m02 = e20 * 2.0f, m11 = e2 * s2f;
    conv(xu, 0, false, m01, m11, m02);
    v2f ls; ls.x = 0.f; ls.y = 0.f;
#pragma unroll
    for (int r = 0; r < 6; ++r) ls += acc[r] * xv[r];
    float lsum = ls.x + ls.y;

#pragma unroll
    for (int o = 1; o < 64; o <<= 1) lsum += __shfl_xor(lsum, o, 64);
    if (l == 0) sred[0][W] = lsum;
    __syncthreads();
    if (t == 0)
        atomicAdd(out, sred[0][0] + sred[0][1] + sred[0][2] + sred[0][3]);
}

extern "C" void kernel_launch(void* const* d_in, const int* in_sizes, int n_in,
                              void* d_out, int out_size, void* d_ws, size_t ws_size,
                              hipStream_t stream) {
    (void)in_sizes; (void)n_in; (void)out_size; (void)d_ws; (void)ws_size;
    const float* hm_gt = (const float*)d_in[0];
    const float* hm_pred = (const float*)d_in[1];
    const int* tops = (const int*)d_in[2];
    float* out = (float*)d_out;

    hipMemsetAsync(out, 0, sizeof(float), stream);
    sinkhorn_colpk<<<dim3(640), dim3(256), 0, stream>>>(hm_gt, hm_pred, tops, out);
}

// Round 7
// 166.945 us; speedup vs baseline: 1.2789x; 1.0324x over previous
//
#include <hip/hip_runtime.h>

#define TINYF 1e-8f
#define NITER 50

typedef __attribute__((ext_vector_type(2))) float v2f;

// Wave-wide DPP shifts (verified gfx950, R5/R6): 0x138 = wave_shr1 (lane i <- i-1,
// 0 into lane 0), 0x130 = wave_shl1 (lane i <- i+1, 0 into lane 63).
__device__ __forceinline__ float wWs(float v) {
    return __int_as_float(__builtin_amdgcn_update_dpp(0, __float_as_int(v), 0x138, 0xf, 0xf, true));
}
__device__ __forceinline__ float wEs(float v) {
    return __int_as_float(__builtin_amdgcn_update_dpp(0, __float_as_int(v), 0x130, 0xf, 0xf, true));
}
__device__ __forceinline__ v2f wW(v2f v) { v2f r; r.x = wWs(v.x); r.y = wWs(v.y); return r; }
__device__ __forceinline__ v2f wE(v2f v) { v2f r; r.x = wEs(v.x); r.y = wEs(v.y); return r; }
__device__ __forceinline__ v2f rcp2(v2f v) {
    v2f r; r.x = __builtin_amdgcn_rcpf(v.x); r.y = __builtin_amdgcn_rcpf(v.y); return r;
}
__device__ __forceinline__ v2f pfma(float k, v2f a, v2f c) {
    v2f kv; kv.x = k; kv.y = k;
    return __builtin_elementwise_fma(kv, a, c);
}

// R6 layout (verified): column-per-lane + vertical 2-band packing. 4 waves =
// one 48x48 crop; lane l (0..47) owns column l; wave W holds rows [6W,6W+6)
// in .x and [24+6W,..) in .y. R7 change: SOFTWARE PIPELINE across the barrier.
// Each half-iteration = combine(+fused rcp, halo-free rows first, boundary
// publishes interleaved) -> DPP prep of the NEW field (no LDS dependence)
// -> barrier. The ~60-instr prep hides ds_write drain + barrier skew; the
// post-barrier halo ds_read latency is hidden under rows 2,3 combine.
// Bit-exact reschedule of R6's arithmetic.
__global__ void __launch_bounds__(256)
sinkhorn_plq(const float* __restrict__ hm_gt,
             const float* __restrict__ hm_pred,
             const int* __restrict__ tops,
             float* __restrict__ out) {
    __shared__ v2f ES[2][6][4][64];
    __shared__ float sred[2][4];

    const int t = threadIdx.x;
    const int W = t >> 6;                  // wave 0..3
    const int l = t & 63;                  // column (0..47 active)
    const bool act = (l < 48);

    // zero guards: .x of slot0 rows 2,3 (band -1) ; .y of slot5 rows 0,1 (band 8)
    {
        const int p = W >> 1, r = W & 1;
        ((float*)&ES[p][0][2 + r][l])[0] = 0.f;
        ((float*)&ES[p][5][r][l])[1] = 0.f;
    }

    const int blk = blockIdx.x;            // ((bi*8+rr)*5+cc)
    const int bi = blk / 40, rr = (blk / 5) % 8, cc = blk % 5;
    const int y0 = tops[(bi * 8 + rr) * 2 + 0];
    const int x0 = tops[(bi * 8 + rr) * 2 + 1];
    const float* srcA = hm_gt + (size_t)(bi * 5 + cc) * 25600;
    const float* srcB = hm_pred + (size_t)(bi * 5 + cc) * 25600;

    // ---- load own two 6-row column segments of both crops; block-reduce sums ----
    v2f va[6], vb[6];
    float sA = 0.f, sB = 0.f;
    const int rbx = y0 + 6 * W;            // .x band
    const int rby = y0 + 24 + 6 * W;       // .y band
#pragma unroll
    for (int r = 0; r < 6; ++r) {
        const int gx = (rbx + r) * 160 + x0 + l;
        const int gy = (rby + r) * 160 + x0 + l;
        va[r].x = act ? srcA[gx] : 0.f;
        va[r].y = act ? srcA[gy] : 0.f;
        vb[r].x = act ? srcB[gx] : 0.f;
        vb[r].y = act ? srcB[gy] : 0.f;
        sA += va[r].x + va[r].y;
        sB += vb[r].x + vb[r].y;
    }
#pragma unroll
    for (int o = 1; o < 64; o <<= 1) {
        sA += __shfl_xor(sA, o, 64);
        sB += __shfl_xor(sB, o, 64);
    }
    if (l == 0) { sred[0][W] = sA; sred[1][W] = sB; }
    __syncthreads();                       // also makes guard zeros visible
    sA = sred[0][0] + sred[0][1] + sred[0][2] + sred[0][3];
    sB = sred[1][0] + sred[1][1] + sred[1][2] + sred[1][3];
    const float nA = 1.0f / (sA + TINYF);
    const float nB = 1.0f / (sB + TINYF);
#pragma unroll
    for (int r = 0; r < 6; ++r) {
        va[r].x *= nA; va[r].y *= nA;
        vb[r].x *= nB; vb[r].y *= nB;
    }

    // Gibbs weights (same expressions as the verified rounds -> same values)
    const float e10 = expf(-1.0f / 0.1f);
    const float e2  = expf(-sqrtf(2.0f) / 0.1f);
    const float e20 = expf(-2.0f / 0.1f);
    const v2f tiny = {TINYF, TINYF};

    v2f xu[6], xv[6];
    const float u0 = 1.0f / 2304.0f;
#pragma unroll
    for (int r = 0; r < 6; ++r) { xu[r].x = act ? u0 : 0.f; xu[r].y = act ? u0 : 0.f; }

    // horizontal prep arrays of the CURRENT field (live across the barrier)
    v2f s1o[6], s2o[6];
    auto prep = [&](const v2f (&x)[6]) {
#pragma unroll
        for (int r = 0; r < 6; ++r) {
            const v2f w1 = wW(x[r]), e1 = wE(x[r]);
            s1o[r] = w1 + e1;
            s2o[r] = wW(w1) + wE(e1);
        }
    };

    // One half-iteration (caller issues __syncthreads() after):
    //   reads halos of field x from parity p; combine rows 2,3 (halo-free)
    //   first, then 1,4, then 0,5; each row fused into o[r] = co[r]*rcp(acc);
    //   boundary rows published to parity q as soon as available; then
    //   prep(o) covers the write drain + barrier skew.
    auto half = [&](const v2f (&x)[6], v2f (&o)[6], const v2f (&co)[6],
                    int p, int q) {
        const v2f um1 = ES[p][W][3][l];        // band rows -1
        const v2f up6 = ES[p][W + 2][0][l];    // band rows +6
        const v2f um2 = ES[p][W][2][l];        // band rows -2
        const v2f up7 = ES[p][W + 2][1][l];    // band rows +7
        v2f a;
        // r=2 (halo-free)
        a = x[2];
        a = pfma(e10, s1o[2] + (x[1] + x[3]), a);
        a = pfma(e2,  s1o[1] + s1o[3], a);
        a = pfma(e20, s2o[2] + (x[0] + x[4]), a);
        o[2] = co[2] * rcp2(a + tiny);
        // r=3 (halo-free)
        a = x[3];
        a = pfma(e10, s1o[3] + (x[2] + x[4]), a);
        a = pfma(e2,  s1o[2] + s1o[4], a);
        a = pfma(e20, s2o[3] + (x[1] + x[5]), a);
        o[3] = co[3] * rcp2(a + tiny);
        // r=1 (needs um1)
        a = x[1];
        a = pfma(e10, s1o[1] + (x[0] + x[2]), a);
        a = pfma(e2,  s1o[0] + s1o[2], a);
        a = pfma(e20, s2o[1] + (um1 + x[3]), a);
        o[1] = co[1] * rcp2(a + tiny);
        ES[q][W + 1][1][l] = o[1];
        // r=4 (needs up6)
        a = x[4];
        a = pfma(e10, s1o[4] + (x[3] + x[5]), a);
        a = pfma(e2,  s1o[3] + s1o[5], a);
        a = pfma(e20, s2o[4] + (x[2] + up6), a);
        o[4] = co[4] * rcp2(a + tiny);
        ES[q][W + 1][2][l] = o[4];
        // halo horizontal sums for rows 0,5
        const v2f s1m = wW(um1) + wE(um1);
        const v2f s1p = wW(up6) + wE(up6);
        // r=0
        a = x[0];
        a = pfma(e10, s1o[0] + (um1 + x[1]), a);
        a = pfma(e2,  s1m + s1o[1], a);
        a = pfma(e20, s2o[0] + (um2 + x[2]), a);
        o[0] = co[0] * rcp2(a + tiny);
        ES[q][W + 1][0][l] = o[0];
        // r=5
        a = x[5];
        a = pfma(e10, s1o[5] + (x[4] + up6), a);
        a = pfma(e2,  s1o[4] + s1p, a);
        a = pfma(e20, s2o[5] + (x[3] + up7), a);
        o[5] = co[5] * rcp2(a + tiny);
        ES[q][W + 1][3][l] = o[5];
        // seams (band3<->band4)
        if (W == 3) {
            ((float*)&ES[q][0][2][l])[1] = o[4].x;
            ((float*)&ES[q][0][3][l])[1] = o[5].x;
        }
        if (W == 0) {
            ((float*)&ES[q][5][0][l])[0] = o[0].y;
            ((float*)&ES[q][5][1][l])[0] = o[1].y;
        }
        // prep of the new field BEFORE the barrier (pure VALU, hides drain/skew)
        prep(o);
    };

    // seed parity 0 with u0 boundary rows; prep(xu); sync
    {
        ES[0][W + 1][0][l] = xu[0];
        ES[0][W + 1][1][l] = xu[1];
        ES[0][W + 1][2][l] = xu[4];
        ES[0][W + 1][3][l] = xu[5];
        if (W == 3) {
            ((float*)&ES[0][0][2][l])[1] = xu[4].x;
            ((float*)&ES[0][0][3][l])[1] = xu[5].x;
        }
        if (W == 0) {
            ((float*)&ES[0][5][0][l])[0] = xu[0].y;
            ((float*)&ES[0][5][1][l])[0] = xu[1].y;
        }
        prep(xu);
        __syncthreads();
    }

    // ---- Sinkhorn iterations: 1 barrier per half-iteration, pipelined ----
#pragma unroll 1
    for (int it = 0; it < NITER; ++it) {
        half(xu, xv, vb, 0, 1);
        __syncthreads();
        half(xv, xu, va, 1, 0);
        __syncthreads();
    }

    // ---- loss: (u @ M) . v, M = K .* dist (center 0; e5/e8 taps dropped) ----
    // Uses s1o/s2o = prep(xu) from the final half; halos from parity 0.
    const float s2f = sqrtf(2.0f);
    const float m01 = e10, m02 = e20 * 2.0f, m11 = e2 * s2f;
    v2f ls = {0.f, 0.f};
    {
        const v2f um1 = ES[0][W][3][l];
        const v2f up6 = ES[0][W + 2][0][l];
        const v2f um2 = ES[0][W][2][l];
        const v2f up7 = ES[0][W + 2][1][l];
        const v2f s1m = wW(um1) + wE(um1);
        const v2f s1p = wW(up6) + wE(up6);
        const v2f zero = {0.f, 0.f};
        v2f a;
        // r=0
        a = pfma(m01, s1o[0] + (um1 + xu[1]), zero);
        a = pfma(m11, s1m + s1o[1], a);
        a = pfma(m02, s2o[0] + (um2 + xu[2]), a);
        ls += a * xv[0];
        // r=1
        a = pfma(m01, s1o[1] + (xu[0] + xu[2]), zero);
        a = pfma(m11, s1o[0] + s1o[2], a);
        a = pfma(m02, s2o[1] + (um1 + xu[3]), a);
        ls += a * xv[1];
        // r=2
        a = pfma(m01, s1o[2] + (xu[1] + xu[3]), zero);
        a = pfma(m11, s1o[1] + s1o[3], a);
        a = pfma(m02, s2o[2] + (xu[0] + xu[4]), a);
        ls += a * xv[2];
        // r=3
        a = pfma(m01, s1o[3] + (xu[2] + xu[4]), zero);
        a = pfma(m11, s1o[2] + s1o[4], a);
        a = pfma(m02, s2o[3] + (xu[1] + xu[5]), a);
        ls += a * xv[3];
        // r=4
        a = pfma(m01, s1o[4] + (xu[3] + xu[5]), zero);
        a = pfma(m11, s1o[3] + s1o[5], a);
        a = pfma(m02, s2o[4] + (xu[2] + up6), a);
        ls += a * xv[4];
        // r=5
        a = pfma(m01, s1o[5] + (xu[4] + up6), zero);
        a = pfma(m11, s1o[4] + s1p, a);
        a = pfma(m02, s2o[5] + (xu[3] + up7), a);
        ls += a * xv[5];
    }
    float lsum = ls.x + ls.y;

#pragma unroll
    for (int o = 1; o < 64; o <<= 1) lsum += __shfl_xor(lsum, o, 64);
    if (l == 0) sred[0][W] = lsum;
    __syncthreads();
    if (t == 0)
        atomicAdd(out, sred[0][0] + sred[0][1] + sred[0][2] + sred[0][3]);
}

extern "C" void kernel_launch(void* const* d_in, const int* in_sizes, int n_in,
                              void* d_out, int out_size, void* d_ws, size_t ws_size,
                              hipStream_t stream) {
    (void)in_sizes; (void)n_in; (void)out_size; (void)d_ws; (void)ws_size;
    const float* hm_gt = (const float*)d_in[0];
    const float* hm_pred = (const float*)d_in[1];
    const int* tops = (const int*)d_in[2];
    float* out = (float*)d_out;

    hipMemsetAsync(out, 0, sizeof(float), stream);
    sinkhorn_plq<<<dim3(640), dim3(256), 0, stream>>>(hm_gt, hm_pred, tops, out);
}